// Round 1
// baseline (1013.635 us; speedup 1.0000x reference)
//
#include <hip/hip_runtime.h>

#define HID 64
#define INDIM 128

__global__ __launch_bounds__(256) void deg_init_k(float* __restrict__ deg, int n) {
    int i = blockIdx.x * blockDim.x + threadIdx.x;
    if (i < n) deg[i] = 1.0f;  // self-loop
}

__global__ __launch_bounds__(256) void deg_count_k(float* __restrict__ deg,
                                                   const int* __restrict__ dst, int E) {
    int e = blockIdx.x * blockDim.x + threadIdx.x;
    if (e < E) atomicAdd(&deg[dst[e]], 1.0f);
}

__global__ __launch_bounds__(256) void dinv_k(float* __restrict__ dinv,
                                              const float* __restrict__ deg, int n) {
    int i = blockIdx.x * blockDim.x + threadIdx.x;
    if (i < n) dinv[i] = 1.0f / sqrtf(deg[i]);  // deg >= 1 always (self-loop)
}

// C[M,64] = act(A[M,K]) @ W[K,64] (+ bias). Thread-per-row, 64 fp32 accumulators.
// W[(k+kk)*64+c] is wave-uniform -> scalar loads; per k: ~1 load + 64 v_fma.
template <int K, bool RELU, bool BIAS>
__global__ __launch_bounds__(64) void gemm_k(const float* __restrict__ A,
                                             const float* __restrict__ W,
                                             const float* __restrict__ bias,
                                             float* __restrict__ C, int M) {
    int row = blockIdx.x * 64 + threadIdx.x;
    if (row >= M) return;
    float acc[HID];
#pragma unroll
    for (int c = 0; c < HID; c++) acc[c] = BIAS ? bias[c] : 0.0f;
    const float* a = A + (long)row * K;
    for (int k = 0; k < K; k += 4) {
        float4 v = *(const float4*)(a + k);
        float av[4] = {v.x, v.y, v.z, v.w};
#pragma unroll
        for (int kk = 0; kk < 4; kk++) {
            float xval = RELU ? fmaxf(av[kk], 0.0f) : av[kk];
#pragma unroll
            for (int c = 0; c < HID; c++)
                acc[c] = fmaf(xval, W[(k + kk) * HID + c], acc[c]);
        }
    }
    float* out = C + (long)row * HID;
#pragma unroll
    for (int c = 0; c < HID; c += 4) {
        float4 o;
        o.x = acc[c]; o.y = acc[c + 1]; o.z = acc[c + 2]; o.w = acc[c + 3];
        *(float4*)(out + c) = o;
    }
}

// agg[i,c] = bias[c] + h[i,c]*dinv[i]^2   (bias + self-loop term)
__global__ __launch_bounds__(256) void agg_init_k(float* __restrict__ out,
                                                  const float* __restrict__ h,
                                                  const float* __restrict__ dinv,
                                                  const float* __restrict__ bias, int n) {
    long t = (long)blockIdx.x * blockDim.x + threadIdx.x;
    if (t >= (long)n * HID) return;
    int i = (int)(t >> 6), c = (int)(t & 63);
    float di = dinv[i];
    out[t] = bias[c] + h[t] * di * di;
}

// wave-per-edge (lane = feature): agg[dst,c] += h[src,c]*dinv[src]*dinv[dst]
__global__ __launch_bounds__(256) void agg_edge_k(float* __restrict__ out,
                                                  const float* __restrict__ h,
                                                  const float* __restrict__ dinv,
                                                  const int* __restrict__ src,
                                                  const int* __restrict__ dst, int E) {
    long t = (long)blockIdx.x * blockDim.x + threadIdx.x;
    if (t >= (long)E * HID) return;
    int e = (int)(t >> 6), c = (int)(t & 63);
    int s = src[e], d = dst[e];
    float norm = dinv[s] * dinv[d];
    atomicAdd(&out[(long)d * HID + c], h[(long)s * HID + c] * norm);
}

extern "C" void kernel_launch(void* const* d_in, const int* in_sizes, int n_in,
                              void* d_out, int out_size, void* d_ws, size_t ws_size,
                              hipStream_t stream) {
    const float* x   = (const float*)d_in[0];
    const int*   ei  = (const int*)d_in[1];
    const float* W1  = (const float*)d_in[2];
    const float* b1  = (const float*)d_in[3];
    const float* W2  = (const float*)d_in[4];
    const float* b2  = (const float*)d_in[5];
    const float* Wfc = (const float*)d_in[6];
    const float* bfc = (const float*)d_in[7];

    int N = in_sizes[0] / INDIM;
    int E = in_sizes[1] / 2;
    const int* src = ei;       // edge_index row 0
    const int* dst = ei + E;   // edge_index row 1

    float* ws   = (float*)d_ws;
    float* deg  = ws;                       // [N]
    float* dinv = deg + N;                  // [N]
    float* bufH = dinv + N;                 // [N,64]  h1 / h2
    float* bufA = bufH + (size_t)N * HID;   // [N,64]  agg1 / agg2
    float* outp = (float*)d_out;

    const int b = 256;
    long NH = (long)N * HID;
    long EH = (long)E * HID;

    // degrees + normalization
    deg_init_k<<<(N + b - 1) / b, b, 0, stream>>>(deg, N);
    deg_count_k<<<(E + b - 1) / b, b, 0, stream>>>(deg, dst, E);
    dinv_k<<<(N + b - 1) / b, b, 0, stream>>>(dinv, deg, N);

    // layer 1: h1 = x @ W1 ; agg1 = b1 + selfloop + scatter ; relu folded into next gemm
    gemm_k<INDIM, false, false><<<(N + 63) / 64, 64, 0, stream>>>(x, W1, nullptr, bufH, N);
    agg_init_k<<<(int)((NH + b - 1) / b), b, 0, stream>>>(bufA, bufH, dinv, b1, N);
    agg_edge_k<<<(int)((EH + b - 1) / b), b, 0, stream>>>(bufA, bufH, dinv, src, dst, E);

    // layer 2: h2 = relu(agg1) @ W2 ; agg2 = b2 + selfloop + scatter
    gemm_k<HID, true, false><<<(N + 63) / 64, 64, 0, stream>>>(bufA, W2, nullptr, bufH, N);
    agg_init_k<<<(int)((NH + b - 1) / b), b, 0, stream>>>(bufA, bufH, dinv, b2, N);
    agg_edge_k<<<(int)((EH + b - 1) / b), b, 0, stream>>>(bufA, bufH, dinv, src, dst, E);

    // fc: out = relu(agg2) @ Wfc + bfc
    gemm_k<HID, true, true><<<(N + 63) / 64, 64, 0, stream>>>(bufA, Wfc, bfc, outp, N);
}

// Round 2
// 725.425 us; speedup vs baseline: 1.3973x; 1.3973x over previous
//
#include <hip/hip_runtime.h>

#define HID 64
#define INDIM 128

// ---------- CSR build ----------

__global__ __launch_bounds__(256) void zero_k(int* __restrict__ p, int n) {
    int i = blockIdx.x * blockDim.x + threadIdx.x;
    if (i < n) p[i] = 0;
}

__global__ __launch_bounds__(256) void hist_k(int* __restrict__ counts,
                                              const int* __restrict__ dst, int E) {
    int e = blockIdx.x * blockDim.x + threadIdx.x;
    if (e < E) atomicAdd(&counts[dst[e]], 1);
}

// per-block exclusive scan: 256 threads x 4 elements = 1024 per block
__global__ __launch_bounds__(256) void scan1_k(const int* __restrict__ counts,
                                               int* __restrict__ rowptr,
                                               int* __restrict__ blocksums, int n) {
    __shared__ int lds[256];
    int base = blockIdx.x * 1024;
    int t = threadIdx.x;
    int v[4]; int sum = 0;
#pragma unroll
    for (int j = 0; j < 4; j++) {
        int idx = base + t * 4 + j;
        v[j] = (idx < n) ? counts[idx] : 0;
        sum += v[j];
    }
    lds[t] = sum; __syncthreads();
    for (int off = 1; off < 256; off <<= 1) {
        int x = (t >= off) ? lds[t - off] : 0;
        __syncthreads();
        lds[t] += x;
        __syncthreads();
    }
    int excl = lds[t] - sum;
    if (t == 255) blocksums[blockIdx.x] = lds[255];
    int run = excl;
#pragma unroll
    for (int j = 0; j < 4; j++) {
        int idx = base + t * 4 + j;
        if (idx < n) rowptr[idx] = run;
        run += v[j];
    }
}

// single-block scan of block sums (nb <= 1024)
__global__ __launch_bounds__(1024) void scan2_k(int* __restrict__ blocksums, int nb) {
    __shared__ int lds[1024];
    int t = threadIdx.x;
    int v = (t < nb) ? blocksums[t] : 0;
    lds[t] = v; __syncthreads();
    for (int off = 1; off < 1024; off <<= 1) {
        int x = (t >= off) ? lds[t - off] : 0;
        __syncthreads();
        lds[t] += x;
        __syncthreads();
    }
    if (t < nb) blocksums[t] = lds[t] - v;  // exclusive
}

__global__ __launch_bounds__(256) void finalize_k(int* __restrict__ rowptr,
                                                  int* __restrict__ cursor,
                                                  float* __restrict__ dinv,
                                                  const int* __restrict__ counts,
                                                  const int* __restrict__ blocksums,
                                                  int n, int E) {
    int i = blockIdx.x * blockDim.x + threadIdx.x;
    if (i < n) {
        int r = rowptr[i] + blocksums[i >> 10];
        rowptr[i] = r;
        cursor[i] = r;
        dinv[i] = rsqrtf(1.0f + (float)counts[i]);  // deg = self-loop + in-degree
    }
    if (i == 0) rowptr[n] = E;
}

__global__ __launch_bounds__(256) void scatter_k(const int* __restrict__ src,
                                                 const int* __restrict__ dst,
                                                 int* __restrict__ cursor,
                                                 int* __restrict__ sorted_src, int E) {
    int e = blockIdx.x * blockDim.x + threadIdx.x;
    if (e < E) {
        int pos = atomicAdd(&cursor[dst[e]], 1);
        sorted_src[pos] = src[e];
    }
}

// ---------- compute ----------

// C[M,64] = act(A[M,K]) @ W[K,64] (+ bias). Thread-per-row, 64 fp32 accumulators.
template <int K, bool RELU, bool BIAS>
__global__ __launch_bounds__(256) void gemm_k(const float* __restrict__ A,
                                              const float* __restrict__ W,
                                              const float* __restrict__ bias,
                                              float* __restrict__ C, int M) {
    int row = blockIdx.x * 256 + threadIdx.x;
    if (row >= M) return;
    float acc[HID];
#pragma unroll
    for (int c = 0; c < HID; c++) acc[c] = BIAS ? bias[c] : 0.0f;
    const float* a = A + (long)row * K;
    for (int k = 0; k < K; k += 4) {
        float4 v = *(const float4*)(a + k);
        float av[4] = {v.x, v.y, v.z, v.w};
#pragma unroll
        for (int kk = 0; kk < 4; kk++) {
            float xval = RELU ? fmaxf(av[kk], 0.0f) : av[kk];
#pragma unroll
            for (int c = 0; c < HID; c++)
                acc[c] = fmaf(xval, W[(k + kk) * HID + c], acc[c]);
        }
    }
    float* out = C + (long)row * HID;
#pragma unroll
    for (int c = 0; c < HID; c += 4) {
        float4 o;
        o.x = acc[c]; o.y = acc[c + 1]; o.z = acc[c + 2]; o.w = acc[c + 3];
        *(float4*)(out + c) = o;
    }
}

// gather aggregation: wave per node, lane = feature.
// out[i,c] = bias[c] + h[i,c]*dinv[i]^2 + sum_in-edges h[s,c]*dinv[s]*dinv[i]
__global__ __launch_bounds__(256) void gather_k(float* __restrict__ out,
                                                const float* __restrict__ h,
                                                const float* __restrict__ dinv,
                                                const float* __restrict__ bias,
                                                const int* __restrict__ rowptr,
                                                const int* __restrict__ sorted_src, int n) {
    int node = blockIdx.x * 4 + (threadIdx.x >> 6);
    int c = threadIdx.x & 63;
    if (node >= n) return;
    float di = dinv[node];
    float acc = bias[c] + h[(long)node * HID + c] * di * di;
    int e0 = rowptr[node], e1 = rowptr[node + 1];
    for (int e = e0; e < e1; e++) {
        int s = sorted_src[e];
        acc = fmaf(h[(long)s * HID + c], dinv[s] * di, acc);
    }
    out[(long)node * HID + c] = acc;
}

extern "C" void kernel_launch(void* const* d_in, const int* in_sizes, int n_in,
                              void* d_out, int out_size, void* d_ws, size_t ws_size,
                              hipStream_t stream) {
    const float* x   = (const float*)d_in[0];
    const int*   ei  = (const int*)d_in[1];
    const float* W1  = (const float*)d_in[2];
    const float* b1  = (const float*)d_in[3];
    const float* W2  = (const float*)d_in[4];
    const float* b2  = (const float*)d_in[5];
    const float* Wfc = (const float*)d_in[6];
    const float* bfc = (const float*)d_in[7];

    int N = in_sizes[0] / INDIM;
    int E = in_sizes[1] / 2;
    const int* src = ei;       // edge_index row 0
    const int* dst = ei + E;   // edge_index row 1

    char* ws = (char*)d_ws;
    int*   counts     = (int*)ws;                         ws += sizeof(int) * (size_t)N;
    int*   rowptr     = (int*)ws;                         ws += sizeof(int) * ((size_t)N + 1);
    int*   cursor     = (int*)ws;                         ws += sizeof(int) * (size_t)N;
    int*   blocksums  = (int*)ws;                         ws += sizeof(int) * 1024;
    float* dinv       = (float*)ws;                       ws += sizeof(float) * (size_t)N;
    int*   sorted_src = (int*)ws;                         ws += sizeof(int) * (size_t)E;
    float* bufH       = (float*)ws;                       ws += sizeof(float) * (size_t)N * HID;
    float* bufA       = (float*)ws;                       ws += sizeof(float) * (size_t)N * HID;
    float* outp       = (float*)d_out;

    const int b = 256;
    int nb_scan = (N + 1023) / 1024;

    // CSR build (per call; no state may survive between calls)
    zero_k<<<(N + b - 1) / b, b, 0, stream>>>(counts, N);
    hist_k<<<(E + b - 1) / b, b, 0, stream>>>(counts, dst, E);
    scan1_k<<<nb_scan, 256, 0, stream>>>(counts, rowptr, blocksums, N);
    scan2_k<<<1, 1024, 0, stream>>>(blocksums, nb_scan);
    finalize_k<<<(N + b - 1) / b, b, 0, stream>>>(rowptr, cursor, dinv, counts, blocksums, N, E);
    scatter_k<<<(E + b - 1) / b, b, 0, stream>>>(src, dst, cursor, sorted_src, E);

    // layer 1
    gemm_k<INDIM, false, false><<<(N + 255) / 256, 256, 0, stream>>>(x, W1, nullptr, bufH, N);
    gather_k<<<(N + 3) / 4, 256, 0, stream>>>(bufA, bufH, dinv, b1, rowptr, sorted_src, N);
    // layer 2 (relu folded into gemm A-read)
    gemm_k<HID, true, false><<<(N + 255) / 256, 256, 0, stream>>>(bufA, W2, nullptr, bufH, N);
    gather_k<<<(N + 3) / 4, 256, 0, stream>>>(bufA, bufH, dinv, b2, rowptr, sorted_src, N);
    // fc
    gemm_k<HID, true, true><<<(N + 255) / 256, 256, 0, stream>>>(bufA, Wfc, bfc, outp, N);
}

// Round 3
// 576.991 us; speedup vs baseline: 1.7568x; 1.2573x over previous
//
#include <hip/hip_runtime.h>

#define HID 64
#define INDIM 128

// ---------- CSR build ----------

__global__ __launch_bounds__(256) void hist_k(int* __restrict__ counts,
                                              const int* __restrict__ dst, int E) {
    int e = blockIdx.x * blockDim.x + threadIdx.x;
    if (e < E) atomicAdd(&counts[dst[e]], 1);
}

// per-block exclusive scan: 256 threads x 4 elements = 1024 per block
__global__ __launch_bounds__(256) void scan1_k(const int* __restrict__ counts,
                                               int* __restrict__ rowptr,
                                               int* __restrict__ blocksums, int n) {
    __shared__ int lds[256];
    int base = blockIdx.x * 1024;
    int t = threadIdx.x;
    int v[4]; int sum = 0;
#pragma unroll
    for (int j = 0; j < 4; j++) {
        int idx = base + t * 4 + j;
        v[j] = (idx < n) ? counts[idx] : 0;
        sum += v[j];
    }
    lds[t] = sum; __syncthreads();
    for (int off = 1; off < 256; off <<= 1) {
        int x = (t >= off) ? lds[t - off] : 0;
        __syncthreads();
        lds[t] += x;
        __syncthreads();
    }
    int excl = lds[t] - sum;
    if (t == 255) blocksums[blockIdx.x] = lds[255];
    int run = excl;
#pragma unroll
    for (int j = 0; j < 4; j++) {
        int idx = base + t * 4 + j;
        if (idx < n) rowptr[idx] = run;
        run += v[j];
    }
}

__global__ __launch_bounds__(1024) void scan2_k(int* __restrict__ blocksums, int nb) {
    __shared__ int lds[1024];
    int t = threadIdx.x;
    int v = (t < nb) ? blocksums[t] : 0;
    lds[t] = v; __syncthreads();
    for (int off = 1; off < 1024; off <<= 1) {
        int x = (t >= off) ? lds[t - off] : 0;
        __syncthreads();
        lds[t] += x;
        __syncthreads();
    }
    if (t < nb) blocksums[t] = lds[t] - v;  // exclusive
}

__global__ __launch_bounds__(256) void finalize_k(int* __restrict__ rowptr,
                                                  int* __restrict__ cursor,
                                                  float* __restrict__ dinv,
                                                  const int* __restrict__ counts,
                                                  const int* __restrict__ blocksums,
                                                  int n, int E) {
    int i = blockIdx.x * blockDim.x + threadIdx.x;
    if (i < n) {
        int r = rowptr[i] + blocksums[i >> 10];
        rowptr[i] = r;
        cursor[i] = r;
        dinv[i] = rsqrtf(1.0f + (float)counts[i]);  // deg = self-loop + in-degree
    }
    if (i == 0) rowptr[n] = E;
}

__global__ __launch_bounds__(256) void scatter_k(const int* __restrict__ src,
                                                 const int* __restrict__ dst,
                                                 int* __restrict__ cursor,
                                                 int* __restrict__ sorted_src, int E) {
    int e = blockIdx.x * blockDim.x + threadIdx.x;
    if (e < E) {
        int pos = atomicAdd(&cursor[dst[e]], 1);
        sorted_src[pos] = src[e];
    }
}

// ---------- compute ----------

// C[M,64] = act(A[M,K]) @ W[K,64] (+bias) (*dinv[row]). Thread-per-row, 64 fp32 acc.
// W index is wave-uniform -> s_load; inner loop is v_fma-bound.
template <int K, bool RELU, bool BIAS, bool SCALE>
__global__ __launch_bounds__(256) void gemm_k(const float* __restrict__ A,
                                              const float* __restrict__ W,
                                              const float* __restrict__ bias,
                                              const float* __restrict__ dinv,
                                              float* __restrict__ C, int M) {
    int row = blockIdx.x * 256 + threadIdx.x;
    if (row >= M) return;
    float acc[HID];
#pragma unroll
    for (int c = 0; c < HID; c++) acc[c] = BIAS ? bias[c] : 0.0f;
    const float* a = A + (long)row * K;
    for (int k = 0; k < K; k += 4) {
        float4 v = *(const float4*)(a + k);
        float av[4] = {v.x, v.y, v.z, v.w};
#pragma unroll
        for (int kk = 0; kk < 4; kk++) {
            float xval = RELU ? fmaxf(av[kk], 0.0f) : av[kk];
#pragma unroll
            for (int c = 0; c < HID; c++)
                acc[c] = fmaf(xval, W[(k + kk) * HID + c], acc[c]);
        }
    }
    float s = SCALE ? dinv[row] : 1.0f;
    float* out = C + (long)row * HID;
#pragma unroll
    for (int c = 0; c < HID; c += 4) {
        float4 o;
        o.x = acc[c] * s; o.y = acc[c + 1] * s; o.z = acc[c + 2] * s; o.w = acc[c + 3] * s;
        *(float4*)(out + c) = o;
    }
}

// gather aggregation: wave per node, lane = feature; hs = h * dinv pre-scaled.
// out[i,c] = bias[c] + dinv[i] * (hs[i,c] + sum_{s in-edges} hs[s,c])
// 8-deep unroll: 8 independent h-loads in flight per wave (latency -> BW bound).
__global__ __launch_bounds__(256) void gather_k(float* __restrict__ out,
                                                const float* __restrict__ hs,
                                                const float* __restrict__ dinv,
                                                const float* __restrict__ bias,
                                                const int* __restrict__ rowptr,
                                                const int* __restrict__ sorted_src, int n) {
    int node = blockIdx.x * 4 + (threadIdx.x >> 6);
    int c = threadIdx.x & 63;
    if (node >= n) return;
    int e0 = rowptr[node], e1 = rowptr[node + 1];
    float a0 = hs[(long)node * HID + c];  // self-loop term
    float a1 = 0.f, a2 = 0.f, a3 = 0.f;
    int e = e0;
    for (; e + 8 <= e1; e += 8) {
        int s0 = sorted_src[e + 0], s1 = sorted_src[e + 1];
        int s2 = sorted_src[e + 2], s3 = sorted_src[e + 3];
        int s4 = sorted_src[e + 4], s5 = sorted_src[e + 5];
        int s6 = sorted_src[e + 6], s7 = sorted_src[e + 7];
        float v0 = hs[(long)s0 * HID + c], v1 = hs[(long)s1 * HID + c];
        float v2 = hs[(long)s2 * HID + c], v3 = hs[(long)s3 * HID + c];
        float v4 = hs[(long)s4 * HID + c], v5 = hs[(long)s5 * HID + c];
        float v6 = hs[(long)s6 * HID + c], v7 = hs[(long)s7 * HID + c];
        a0 += v0; a1 += v1; a2 += v2; a3 += v3;
        a0 += v4; a1 += v5; a2 += v6; a3 += v7;
    }
    for (; e + 4 <= e1; e += 4) {
        int s0 = sorted_src[e + 0], s1 = sorted_src[e + 1];
        int s2 = sorted_src[e + 2], s3 = sorted_src[e + 3];
        float v0 = hs[(long)s0 * HID + c], v1 = hs[(long)s1 * HID + c];
        float v2 = hs[(long)s2 * HID + c], v3 = hs[(long)s3 * HID + c];
        a0 += v0; a1 += v1; a2 += v2; a3 += v3;
    }
    for (; e < e1; e++) a1 += hs[(long)sorted_src[e] * HID + c];
    float acc = (a0 + a1) + (a2 + a3);
    out[(long)node * HID + c] = fmaf(dinv[node], acc, bias[c]);
}

extern "C" void kernel_launch(void* const* d_in, const int* in_sizes, int n_in,
                              void* d_out, int out_size, void* d_ws, size_t ws_size,
                              hipStream_t stream) {
    const float* x   = (const float*)d_in[0];
    const int*   ei  = (const int*)d_in[1];
    const float* W1  = (const float*)d_in[2];
    const float* b1  = (const float*)d_in[3];
    const float* W2  = (const float*)d_in[4];
    const float* b2  = (const float*)d_in[5];
    const float* Wfc = (const float*)d_in[6];
    const float* bfc = (const float*)d_in[7];

    int N = in_sizes[0] / INDIM;
    int E = in_sizes[1] / 2;
    const int* src = ei;       // edge_index row 0
    const int* dst = ei + E;   // edge_index row 1

    char* ws = (char*)d_ws;
    int*   counts     = (int*)ws;                         ws += sizeof(int) * (size_t)N;
    int*   rowptr     = (int*)ws;                         ws += sizeof(int) * ((size_t)N + 1);
    int*   cursor     = (int*)ws;                         ws += sizeof(int) * (size_t)N;
    int*   blocksums  = (int*)ws;                         ws += sizeof(int) * 1024;
    float* dinv       = (float*)ws;                       ws += sizeof(float) * (size_t)N;
    int*   sorted_src = (int*)ws;                         ws += sizeof(int) * (size_t)E;
    float* bufH       = (float*)ws;                       ws += sizeof(float) * (size_t)N * HID;
    float* bufA       = (float*)ws;                       ws += sizeof(float) * (size_t)N * HID;
    float* outp       = (float*)d_out;

    const int b = 256;
    int nb_scan = (N + 1023) / 1024;

    // CSR build (per call; no state survives between calls)
    hipMemsetAsync(counts, 0, sizeof(int) * (size_t)N, stream);
    hist_k<<<(E + b - 1) / b, b, 0, stream>>>(counts, dst, E);
    scan1_k<<<nb_scan, 256, 0, stream>>>(counts, rowptr, blocksums, N);
    scan2_k<<<1, 1024, 0, stream>>>(blocksums, nb_scan);
    finalize_k<<<(N + b - 1) / b, b, 0, stream>>>(rowptr, cursor, dinv, counts, blocksums, N, E);
    scatter_k<<<(E + b - 1) / b, b, 0, stream>>>(src, dst, cursor, sorted_src, E);

    // layer 1: hs1 = (x @ W1) * dinv
    gemm_k<INDIM, false, false, true><<<(N + 255) / 256, 256, 0, stream>>>(x, W1, nullptr, dinv, bufH, N);
    gather_k<<<(N + 3) / 4, 256, 0, stream>>>(bufA, bufH, dinv, b1, rowptr, sorted_src, N);
    // layer 2: hs2 = (relu(agg1) @ W2) * dinv
    gemm_k<HID, true, false, true><<<(N + 255) / 256, 256, 0, stream>>>(bufA, W2, nullptr, dinv, bufH, N);
    gather_k<<<(N + 3) / 4, 256, 0, stream>>>(bufA, bufH, dinv, b2, rowptr, sorted_src, N);
    // fc: out = relu(agg2) @ Wfc + bfc
    gemm_k<HID, true, true, false><<<(N + 255) / 256, 256, 0, stream>>>(bufA, Wfc, bfc, nullptr, outp, N);
}

// Round 4
// 457.127 us; speedup vs baseline: 2.2174x; 1.2622x over previous
//
#include <hip/hip_runtime.h>

#define HID 64
#define INDIM 128
#define BK_SHIFT 9           // 512 nodes per bucket
#define BK_NODES 512
#define NBK_MAX 256          // max buckets (N <= 131072)
#define PB_BLOCKS 512
#define PB_MAXI 16           // supports E <= 512*256*16 = 2.097M

// ---------- CSR build: bucketed counting sort by dst ----------

// Pass A: bucket histogram (LDS-staged)
__global__ __launch_bounds__(256) void bhist_k(const int* __restrict__ dst,
                                               int* __restrict__ bucket_counts, int E) {
    __shared__ int h[NBK_MAX];
    for (int i = threadIdx.x; i < NBK_MAX; i += 256) h[i] = 0;
    __syncthreads();
    for (long e = (long)blockIdx.x * 256 + threadIdx.x; e < E; e += (long)gridDim.x * 256)
        atomicAdd(&h[dst[e] >> BK_SHIFT], 1);
    __syncthreads();
    for (int i = threadIdx.x; i < NBK_MAX; i += 256)
        if (h[i]) atomicAdd(&bucket_counts[i], h[i]);
}

// Scan bucket counts -> bucket_base (exclusive); init bucket_cursor; rowptr[N]=E
__global__ __launch_bounds__(256) void bscan_k(const int* __restrict__ bucket_counts,
                                               int* __restrict__ bucket_base,
                                               int* __restrict__ bucket_cursor,
                                               int* __restrict__ rowptr,
                                               int nb, int N, int E) {
    __shared__ int lds[256];
    int t = threadIdx.x;
    int v = (t < nb) ? bucket_counts[t] : 0;
    lds[t] = v; __syncthreads();
    for (int off = 1; off < 256; off <<= 1) {
        int x = (t >= off) ? lds[t - off] : 0;
        __syncthreads();
        lds[t] += x;
        __syncthreads();
    }
    int excl = lds[t] - v;
    if (t < nb) { bucket_base[t] = excl; bucket_cursor[t] = excl; }
    if (t == 0) rowptr[N] = E;
}

// Pass B: partition edges into bucket regions (write-combined runs per block)
__global__ __launch_bounds__(256) void bpart_k(const int* __restrict__ src,
                                               const int* __restrict__ dst,
                                               int* __restrict__ bucket_cursor,
                                               int2* __restrict__ bucketed, int E) {
    __shared__ int hist[NBK_MAX];
    __shared__ int base[NBK_MAX];
    for (int i = threadIdx.x; i < NBK_MAX; i += 256) hist[i] = 0;
    __syncthreads();
    int code[PB_MAXI];
#pragma unroll
    for (int i = 0; i < PB_MAXI; i++) {
        code[i] = -1;
        long e = (long)i * (PB_BLOCKS * 256) + (long)blockIdx.x * 256 + threadIdx.x;
        if (e < E) {
            int b = dst[e] >> BK_SHIFT;
            int p = atomicAdd(&hist[b], 1);   // p < 4096 (block total)
            code[i] = (b << 12) | p;
        }
    }
    __syncthreads();
    for (int i = threadIdx.x; i < NBK_MAX; i += 256)
        base[i] = hist[i] ? atomicAdd(&bucket_cursor[i], hist[i]) : 0;
    __syncthreads();
#pragma unroll
    for (int i = 0; i < PB_MAXI; i++) {
        long e = (long)i * (PB_BLOCKS * 256) + (long)blockIdx.x * 256 + threadIdx.x;
        if (e < E) {
            int b = code[i] >> 12, p = code[i] & 0xFFF;
            bucketed[base[b] + p] = make_int2(src[e], dst[e]);
        }
    }
}

// Pass C: per-bucket counting sort (LDS cursors); also emits rowptr + dinv
__global__ __launch_bounds__(256) void bsort_k(const int2* __restrict__ bucketed,
                                               const int* __restrict__ bucket_base,
                                               const int* __restrict__ bucket_counts,
                                               int* __restrict__ rowptr,
                                               int* __restrict__ sorted_src,
                                               float* __restrict__ dinv, int N) {
    __shared__ int deg[BK_NODES];
    __shared__ int cur[BK_NODES];
    __shared__ int sb[256];
    int b = blockIdx.x;
    int nstart = b << BK_SHIFT;
    int ncnt = min(BK_NODES, N - nstart);
    int t = threadIdx.x;
    deg[t] = 0; deg[t + 256] = 0;
    __syncthreads();
    int estart = bucket_base[b], ecnt = bucket_counts[b];
    for (int j = t; j < ecnt; j += 256)
        atomicAdd(&deg[bucketed[estart + j].y - nstart], 1);
    __syncthreads();
    // exclusive scan of deg[512]: 2 elems/thread
    int v0 = deg[2 * t], v1 = deg[2 * t + 1];
    int s = v0 + v1;
    sb[t] = s; __syncthreads();
    for (int off = 1; off < 256; off <<= 1) {
        int x = (t >= off) ? sb[t - off] : 0;
        __syncthreads();
        sb[t] += x;
        __syncthreads();
    }
    int excl = sb[t] - s;
    cur[2 * t] = excl;
    cur[2 * t + 1] = excl + v0;
    __syncthreads();
    for (int i = t; i < ncnt; i += 256) {
        rowptr[nstart + i] = estart + cur[i];
        dinv[nstart + i] = rsqrtf(1.0f + (float)deg[i]);  // deg + self-loop
    }
    __syncthreads();
    for (int j = t; j < ecnt; j += 256) {
        int2 e = bucketed[estart + j];
        int p = atomicAdd(&cur[e.y - nstart], 1);
        sorted_src[estart + p] = e.x;
    }
}

// ---------- compute ----------

// C[M,64] = act(A[M,K]) @ W[K,64] (+bias) (*dinv[row]). Thread-per-row, 64 fp32 acc.
template <int K, bool RELU, bool BIAS, bool SCALE>
__global__ __launch_bounds__(256) void gemm_k(const float* __restrict__ A,
                                              const float* __restrict__ W,
                                              const float* __restrict__ bias,
                                              const float* __restrict__ dinv,
                                              float* __restrict__ C, int M) {
    int row = blockIdx.x * 256 + threadIdx.x;
    if (row >= M) return;
    float acc[HID];
#pragma unroll
    for (int c = 0; c < HID; c++) acc[c] = BIAS ? bias[c] : 0.0f;
    const float* a = A + (long)row * K;
    for (int k = 0; k < K; k += 4) {
        float4 v = *(const float4*)(a + k);
        float av[4] = {v.x, v.y, v.z, v.w};
#pragma unroll
        for (int kk = 0; kk < 4; kk++) {
            float xval = RELU ? fmaxf(av[kk], 0.0f) : av[kk];
#pragma unroll
            for (int c = 0; c < HID; c++)
                acc[c] = fmaf(xval, W[(k + kk) * HID + c], acc[c]);
        }
    }
    float s = SCALE ? dinv[row] : 1.0f;
    float* out = C + (long)row * HID;
#pragma unroll
    for (int c = 0; c < HID; c += 4) {
        float4 o;
        o.x = acc[c] * s; o.y = acc[c + 1] * s; o.z = acc[c + 2] * s; o.w = acc[c + 3] * s;
        *(float4*)(out + c) = o;
    }
}

// gather aggregation: wave per node, lane = feature; hs = h * dinv pre-scaled.
// out[i,c] = bias[c] + dinv[i] * (hs[i,c] + sum_{s in-edges} hs[s,c])
__global__ __launch_bounds__(256) void gather_k(float* __restrict__ out,
                                                const float* __restrict__ hs,
                                                const float* __restrict__ dinv,
                                                const float* __restrict__ bias,
                                                const int* __restrict__ rowptr,
                                                const int* __restrict__ sorted_src, int n) {
    int node = blockIdx.x * 4 + (threadIdx.x >> 6);
    int c = threadIdx.x & 63;
    if (node >= n) return;
    int e0 = rowptr[node], e1 = rowptr[node + 1];
    float a0 = hs[(long)node * HID + c];  // self-loop term
    float a1 = 0.f, a2 = 0.f, a3 = 0.f;
    int e = e0;
    for (; e + 8 <= e1; e += 8) {
        int s0 = sorted_src[e + 0], s1 = sorted_src[e + 1];
        int s2 = sorted_src[e + 2], s3 = sorted_src[e + 3];
        int s4 = sorted_src[e + 4], s5 = sorted_src[e + 5];
        int s6 = sorted_src[e + 6], s7 = sorted_src[e + 7];
        float v0 = hs[(long)s0 * HID + c], v1 = hs[(long)s1 * HID + c];
        float v2 = hs[(long)s2 * HID + c], v3 = hs[(long)s3 * HID + c];
        float v4 = hs[(long)s4 * HID + c], v5 = hs[(long)s5 * HID + c];
        float v6 = hs[(long)s6 * HID + c], v7 = hs[(long)s7 * HID + c];
        a0 += v0; a1 += v1; a2 += v2; a3 += v3;
        a0 += v4; a1 += v5; a2 += v6; a3 += v7;
    }
    for (; e + 4 <= e1; e += 4) {
        int s0 = sorted_src[e + 0], s1 = sorted_src[e + 1];
        int s2 = sorted_src[e + 2], s3 = sorted_src[e + 3];
        float v0 = hs[(long)s0 * HID + c], v1 = hs[(long)s1 * HID + c];
        float v2 = hs[(long)s2 * HID + c], v3 = hs[(long)s3 * HID + c];
        a0 += v0; a1 += v1; a2 += v2; a3 += v3;
    }
    for (; e < e1; e++) a1 += hs[(long)sorted_src[e] * HID + c];
    float acc = (a0 + a1) + (a2 + a3);
    out[(long)node * HID + c] = fmaf(dinv[node], acc, bias[c]);
}

extern "C" void kernel_launch(void* const* d_in, const int* in_sizes, int n_in,
                              void* d_out, int out_size, void* d_ws, size_t ws_size,
                              hipStream_t stream) {
    const float* x   = (const float*)d_in[0];
    const int*   ei  = (const int*)d_in[1];
    const float* W1  = (const float*)d_in[2];
    const float* b1  = (const float*)d_in[3];
    const float* W2  = (const float*)d_in[4];
    const float* b2  = (const float*)d_in[5];
    const float* Wfc = (const float*)d_in[6];
    const float* bfc = (const float*)d_in[7];

    int N = in_sizes[0] / INDIM;
    int E = in_sizes[1] / 2;
    const int* src = ei;       // edge_index row 0
    const int* dst = ei + E;   // edge_index row 1
    int nb = (N + BK_NODES - 1) >> BK_SHIFT;

    char* ws = (char*)d_ws;
    int*   rowptr        = (int*)ws;   ws += sizeof(int) * ((size_t)N + 1);
    float* dinv          = (float*)ws; ws += sizeof(float) * (size_t)N;
    int*   bucket_counts = (int*)ws;   ws += sizeof(int) * NBK_MAX;
    int*   bucket_base   = (int*)ws;   ws += sizeof(int) * NBK_MAX;
    int*   bucket_cursor = (int*)ws;   ws += sizeof(int) * NBK_MAX;
    int*   sorted_src    = (int*)ws;   ws += sizeof(int) * (size_t)E;
    float* bufH          = (float*)ws; ws += sizeof(float) * (size_t)N * HID;
    float* bufA          = (float*)ws; ws += sizeof(float) * (size_t)N * HID;
    int2*  bucketed      = (int2*)bufA;  // aliased: build finishes before bufA's first use
    float* outp          = (float*)d_out;

    // CSR build (per call; no state survives between calls)
    hipMemsetAsync(bucket_counts, 0, sizeof(int) * NBK_MAX, stream);
    bhist_k<<<PB_BLOCKS, 256, 0, stream>>>(dst, bucket_counts, E);
    bscan_k<<<1, 256, 0, stream>>>(bucket_counts, bucket_base, bucket_cursor, rowptr, nb, N, E);
    bpart_k<<<PB_BLOCKS, 256, 0, stream>>>(src, dst, bucket_cursor, bucketed, E);
    bsort_k<<<nb, 256, 0, stream>>>(bucketed, bucket_base, bucket_counts, rowptr, sorted_src, dinv, N);

    // layer 1: hs1 = (x @ W1) * dinv
    gemm_k<INDIM, false, false, true><<<(N + 255) / 256, 256, 0, stream>>>(x, W1, nullptr, dinv, bufH, N);
    gather_k<<<(N + 3) / 4, 256, 0, stream>>>(bufA, bufH, dinv, b1, rowptr, sorted_src, N);
    // layer 2: hs2 = (relu(agg1) @ W2) * dinv
    gemm_k<HID, true, false, true><<<(N + 255) / 256, 256, 0, stream>>>(bufA, W2, nullptr, dinv, bufH, N);
    gather_k<<<(N + 3) / 4, 256, 0, stream>>>(bufA, bufH, dinv, b2, rowptr, sorted_src, N);
    // fc: out = relu(agg2) @ Wfc + bfc
    gemm_k<HID, true, true, false><<<(N + 255) / 256, 256, 0, stream>>>(bufA, Wfc, bfc, nullptr, outp, N);
}

// Round 5
// 408.243 us; speedup vs baseline: 2.4829x; 1.1197x over previous
//
#include <hip/hip_runtime.h>
#include <hip/hip_bf16.h>

#define HID 64
#define INDIM 128
#define BK_SHIFT 9           // 512 nodes per bucket
#define BK_NODES 512
#define NBK_MAX 256          // max buckets (N <= 131072)
#define PB_BLOCKS 512
#define PB_MAXI 16           // supports E <= 512*256*16 = 2.097M

// ---------- CSR build: bucketed counting sort by dst ----------

__global__ __launch_bounds__(256) void bhist_k(const int* __restrict__ dst,
                                               int* __restrict__ bucket_counts, int E) {
    __shared__ int h[NBK_MAX];
    for (int i = threadIdx.x; i < NBK_MAX; i += 256) h[i] = 0;
    __syncthreads();
    for (long e = (long)blockIdx.x * 256 + threadIdx.x; e < E; e += (long)gridDim.x * 256)
        atomicAdd(&h[dst[e] >> BK_SHIFT], 1);
    __syncthreads();
    for (int i = threadIdx.x; i < NBK_MAX; i += 256)
        if (h[i]) atomicAdd(&bucket_counts[i], h[i]);
}

__global__ __launch_bounds__(256) void bscan_k(const int* __restrict__ bucket_counts,
                                               int* __restrict__ bucket_base,
                                               int* __restrict__ bucket_cursor,
                                               int* __restrict__ rowptr,
                                               int nb, int N, int E) {
    __shared__ int lds[256];
    int t = threadIdx.x;
    int v = (t < nb) ? bucket_counts[t] : 0;
    lds[t] = v; __syncthreads();
    for (int off = 1; off < 256; off <<= 1) {
        int x = (t >= off) ? lds[t - off] : 0;
        __syncthreads();
        lds[t] += x;
        __syncthreads();
    }
    int excl = lds[t] - v;
    if (t < nb) { bucket_base[t] = excl; bucket_cursor[t] = excl; }
    if (t == 0) rowptr[N] = E;
}

__global__ __launch_bounds__(256) void bpart_k(const int* __restrict__ src,
                                               const int* __restrict__ dst,
                                               int* __restrict__ bucket_cursor,
                                               int2* __restrict__ bucketed, int E) {
    __shared__ int hist[NBK_MAX];
    __shared__ int base[NBK_MAX];
    for (int i = threadIdx.x; i < NBK_MAX; i += 256) hist[i] = 0;
    __syncthreads();
    int code[PB_MAXI];
#pragma unroll
    for (int i = 0; i < PB_MAXI; i++) {
        code[i] = -1;
        long e = (long)i * (PB_BLOCKS * 256) + (long)blockIdx.x * 256 + threadIdx.x;
        if (e < E) {
            int b = dst[e] >> BK_SHIFT;
            int p = atomicAdd(&hist[b], 1);   // p < 4096 (block total)
            code[i] = (b << 12) | p;
        }
    }
    __syncthreads();
    for (int i = threadIdx.x; i < NBK_MAX; i += 256)
        base[i] = hist[i] ? atomicAdd(&bucket_cursor[i], hist[i]) : 0;
    __syncthreads();
#pragma unroll
    for (int i = 0; i < PB_MAXI; i++) {
        long e = (long)i * (PB_BLOCKS * 256) + (long)blockIdx.x * 256 + threadIdx.x;
        if (e < E) {
            int b = code[i] >> 12, p = code[i] & 0xFFF;
            bucketed[base[b] + p] = make_int2(src[e], dst[e]);
        }
    }
}

__global__ __launch_bounds__(256) void bsort_k(const int2* __restrict__ bucketed,
                                               const int* __restrict__ bucket_base,
                                               const int* __restrict__ bucket_counts,
                                               int* __restrict__ rowptr,
                                               int* __restrict__ sorted_src,
                                               float* __restrict__ dinv, int N) {
    __shared__ int deg[BK_NODES];
    __shared__ int cur[BK_NODES];
    __shared__ int sb[256];
    int b = blockIdx.x;
    int nstart = b << BK_SHIFT;
    int ncnt = min(BK_NODES, N - nstart);
    int t = threadIdx.x;
    deg[t] = 0; deg[t + 256] = 0;
    __syncthreads();
    int estart = bucket_base[b], ecnt = bucket_counts[b];
    for (int j = t; j < ecnt; j += 256)
        atomicAdd(&deg[bucketed[estart + j].y - nstart], 1);
    __syncthreads();
    int v0 = deg[2 * t], v1 = deg[2 * t + 1];
    int s = v0 + v1;
    sb[t] = s; __syncthreads();
    for (int off = 1; off < 256; off <<= 1) {
        int x = (t >= off) ? sb[t - off] : 0;
        __syncthreads();
        sb[t] += x;
        __syncthreads();
    }
    int excl = sb[t] - s;
    cur[2 * t] = excl;
    cur[2 * t + 1] = excl + v0;
    __syncthreads();
    for (int i = t; i < ncnt; i += 256) {
        rowptr[nstart + i] = estart + cur[i];
        dinv[nstart + i] = rsqrtf(1.0f + (float)deg[i]);  // deg + self-loop
    }
    __syncthreads();
    for (int j = t; j < ecnt; j += 256) {
        int2 e = bucketed[estart + j];
        int p = atomicAdd(&cur[e.y - nstart], 1);
        sorted_src[estart + p] = e.x;
    }
}

// ---------- compute ----------

// C[M,64] = act(A[M,K]) @ W[K,64] (+bias) (*dinv[row]). Thread-per-row, 64 fp32 acc.
// W staged in LDS; per kk: 16 ds_read_b128 (same-addr broadcast, free) + 64 v_fma.
template <int K, bool RELU, bool BIAS, bool SCALE, typename OutT>
__global__ __launch_bounds__(256) void gemm_k(const float* __restrict__ A,
                                              const float* __restrict__ W,
                                              const float* __restrict__ bias,
                                              const float* __restrict__ dinv,
                                              OutT* __restrict__ C, int M) {
    __shared__ float lw[K * HID];
    for (int i = threadIdx.x; i < K * HID / 4; i += 256)
        ((float4*)lw)[i] = ((const float4*)W)[i];
    __syncthreads();
    int row = blockIdx.x * 256 + threadIdx.x;
    if (row >= M) return;
    float acc[HID];
#pragma unroll
    for (int c = 0; c < HID; c++) acc[c] = BIAS ? bias[c] : 0.0f;
    const float* a = A + (long)row * K;
    for (int k = 0; k < K; k += 4) {
        float4 v = *(const float4*)(a + k);
        float av[4] = {v.x, v.y, v.z, v.w};
#pragma unroll
        for (int kk = 0; kk < 4; kk++) {
            float xv = RELU ? fmaxf(av[kk], 0.0f) : av[kk];
            const float4* wr = (const float4*)(lw + (k + kk) * HID);
#pragma unroll
            for (int c4 = 0; c4 < 16; c4++) {
                float4 w = wr[c4];
                acc[4 * c4 + 0] = fmaf(xv, w.x, acc[4 * c4 + 0]);
                acc[4 * c4 + 1] = fmaf(xv, w.y, acc[4 * c4 + 1]);
                acc[4 * c4 + 2] = fmaf(xv, w.z, acc[4 * c4 + 2]);
                acc[4 * c4 + 3] = fmaf(xv, w.w, acc[4 * c4 + 3]);
            }
        }
    }
    float s = SCALE ? dinv[row] : 1.0f;
    if constexpr (sizeof(OutT) == 4) {  // fp32 out
        float* out = (float*)C + (long)row * HID;
#pragma unroll
        for (int c = 0; c < HID; c += 4) {
            float4 o;
            o.x = acc[c] * s; o.y = acc[c + 1] * s;
            o.z = acc[c + 2] * s; o.w = acc[c + 3] * s;
            *(float4*)(out + c) = o;
        }
    } else {  // bf16 out
        __hip_bfloat16* out = (__hip_bfloat16*)C + (long)row * HID;
#pragma unroll
        for (int c = 0; c < HID; c += 8) {
            union { uint4 u; __hip_bfloat16 h[8]; } p;
#pragma unroll
            for (int j = 0; j < 8; j++) p.h[j] = __float2bfloat16(acc[c + j] * s);
            *(uint4*)(out + c) = p.u;
        }
    }
}

// gather aggregation: wave per node, lane = feature; hs = (h * dinv) in bf16.
// out[i,c] = bias[c] + dinv[i] * (hs[i,c] + sum_{s in-edges} hs[s,c])
__global__ __launch_bounds__(256) void gather_k(float* __restrict__ out,
                                                const __hip_bfloat16* __restrict__ hs,
                                                const float* __restrict__ dinv,
                                                const float* __restrict__ bias,
                                                const int* __restrict__ rowptr,
                                                const int* __restrict__ sorted_src, int n) {
    int node = blockIdx.x * 4 + (threadIdx.x >> 6);
    int c = threadIdx.x & 63;
    if (node >= n) return;
    int e0 = rowptr[node], e1 = rowptr[node + 1];
    float a0 = __bfloat162float(hs[(long)node * HID + c]);  // self-loop term
    float a1 = 0.f, a2 = 0.f, a3 = 0.f;
    int e = e0;
    for (; e + 8 <= e1; e += 8) {
        int s0 = sorted_src[e + 0], s1 = sorted_src[e + 1];
        int s2 = sorted_src[e + 2], s3 = sorted_src[e + 3];
        int s4 = sorted_src[e + 4], s5 = sorted_src[e + 5];
        int s6 = sorted_src[e + 6], s7 = sorted_src[e + 7];
        float v0 = __bfloat162float(hs[(long)s0 * HID + c]);
        float v1 = __bfloat162float(hs[(long)s1 * HID + c]);
        float v2 = __bfloat162float(hs[(long)s2 * HID + c]);
        float v3 = __bfloat162float(hs[(long)s3 * HID + c]);
        float v4 = __bfloat162float(hs[(long)s4 * HID + c]);
        float v5 = __bfloat162float(hs[(long)s5 * HID + c]);
        float v6 = __bfloat162float(hs[(long)s6 * HID + c]);
        float v7 = __bfloat162float(hs[(long)s7 * HID + c]);
        a0 += v0; a1 += v1; a2 += v2; a3 += v3;
        a0 += v4; a1 += v5; a2 += v6; a3 += v7;
    }
    for (; e + 4 <= e1; e += 4) {
        int s0 = sorted_src[e + 0], s1 = sorted_src[e + 1];
        int s2 = sorted_src[e + 2], s3 = sorted_src[e + 3];
        float v0 = __bfloat162float(hs[(long)s0 * HID + c]);
        float v1 = __bfloat162float(hs[(long)s1 * HID + c]);
        float v2 = __bfloat162float(hs[(long)s2 * HID + c]);
        float v3 = __bfloat162float(hs[(long)s3 * HID + c]);
        a0 += v0; a1 += v1; a2 += v2; a3 += v3;
    }
    for (; e < e1; e++) a1 += __bfloat162float(hs[(long)sorted_src[e] * HID + c]);
    float acc = (a0 + a1) + (a2 + a3);
    out[(long)node * HID + c] = fmaf(dinv[node], acc, bias[c]);
}

extern "C" void kernel_launch(void* const* d_in, const int* in_sizes, int n_in,
                              void* d_out, int out_size, void* d_ws, size_t ws_size,
                              hipStream_t stream) {
    const float* x   = (const float*)d_in[0];
    const int*   ei  = (const int*)d_in[1];
    const float* W1  = (const float*)d_in[2];
    const float* b1  = (const float*)d_in[3];
    const float* W2  = (const float*)d_in[4];
    const float* b2  = (const float*)d_in[5];
    const float* Wfc = (const float*)d_in[6];
    const float* bfc = (const float*)d_in[7];

    int N = in_sizes[0] / INDIM;
    int E = in_sizes[1] / 2;
    const int* src = ei;       // edge_index row 0
    const int* dst = ei + E;   // edge_index row 1
    int nb = (N + BK_NODES - 1) >> BK_SHIFT;

    char* ws = (char*)d_ws;
    int*   rowptr        = (int*)ws;   ws += sizeof(int) * ((size_t)N + 1);
    float* dinv          = (float*)ws; ws += sizeof(float) * (size_t)N;
    int*   bucket_counts = (int*)ws;   ws += sizeof(int) * NBK_MAX;
    int*   bucket_base   = (int*)ws;   ws += sizeof(int) * NBK_MAX;
    int*   bucket_cursor = (int*)ws;   ws += sizeof(int) * NBK_MAX;
    int*   sorted_src    = (int*)ws;   ws += sizeof(int) * (size_t)E;
    __hip_bfloat16* bufH = (__hip_bfloat16*)ws; ws += sizeof(__hip_bfloat16) * (size_t)N * HID;
    ws = (char*)(((size_t)ws + 15) & ~(size_t)15);
    float* bufA          = (float*)ws; ws += sizeof(float) * (size_t)N * HID;
    int2*  bucketed      = (int2*)bufA;  // aliased: build finishes before bufA's first use
    float* outp          = (float*)d_out;

    // CSR build (per call; no state survives between calls)
    hipMemsetAsync(bucket_counts, 0, sizeof(int) * NBK_MAX, stream);
    bhist_k<<<PB_BLOCKS, 256, 0, stream>>>(dst, bucket_counts, E);
    bscan_k<<<1, 256, 0, stream>>>(bucket_counts, bucket_base, bucket_cursor, rowptr, nb, N, E);
    bpart_k<<<PB_BLOCKS, 256, 0, stream>>>(src, dst, bucket_cursor, bucketed, E);
    bsort_k<<<nb, 256, 0, stream>>>(bucketed, bucket_base, bucket_counts, rowptr, sorted_src, dinv, N);

    // layer 1: hs1 = (x @ W1) * dinv   (bf16)
    gemm_k<INDIM, false, false, true, __hip_bfloat16>
        <<<(N + 255) / 256, 256, 0, stream>>>(x, W1, nullptr, dinv, bufH, N);
    gather_k<<<(N + 3) / 4, 256, 0, stream>>>(bufA, bufH, dinv, b1, rowptr, sorted_src, N);
    // layer 2: hs2 = (relu(agg1) @ W2) * dinv   (bf16)
    gemm_k<HID, true, false, true, __hip_bfloat16>
        <<<(N + 255) / 256, 256, 0, stream>>>(bufA, W2, nullptr, dinv, bufH, N);
    gather_k<<<(N + 3) / 4, 256, 0, stream>>>(bufA, bufH, dinv, b2, rowptr, sorted_src, N);
    // fc: out = relu(agg2) @ Wfc + bfc   (fp32)
    gemm_k<HID, true, true, false, float>
        <<<(N + 255) / 256, 256, 0, stream>>>(bufA, Wfc, bfc, nullptr, outp, N);
}